// Round 1
// baseline (332.065 us; speedup 1.0000x reference)
//
#include <hip/hip_runtime.h>
#include <math.h>

#define RADIUS    1.3f
#define COARSE    16
#define FINE      4
#define NUM_ATOMS 16
#define DATA_DIM  28
#define N_INTR    217
#define STEPF     0.020634920634920634f

#define CELLS      64            // 4*4*4 fine cells
#define LDS_STRIDE 17            // float4 per cell: 16 atoms + 1 pad

__device__ __forceinline__ float sigmoidf_(float x) {
    return 1.0f / (1.0f + expf(-x));
}

__global__ __launch_bounds__(256, 4)
void plenoxel_fwd(const float* __restrict__ rays_o,
                  const float* __restrict__ rays_d,
                  const float* __restrict__ cgrid,
                  const float* __restrict__ atoms,
                  float* __restrict__ out,
                  int n_rays)
{
    __shared__ float4 ldsR[CELLS * LDS_STRIDE];   // 17408 B: SH-folded dictionary
    __shared__ float  scanbuf[256];
    __shared__ float  partials[4 * 5];

    const int ray = blockIdx.x;
    const int tid = threadIdx.x;
    if (ray >= n_rays) return;

    // ---- per-ray setup (redundant per thread; cheap) ----
    const float ox = rays_o[ray * 3 + 0], oy = rays_o[ray * 3 + 1], oz = rays_o[ray * 3 + 2];
    const float dx = rays_d[ray * 3 + 0], dy = rays_d[ray * 3 + 1], dz = rays_d[ray * 3 + 2];

    const float sdx = (fabsf(dx) < 1e-9f) ? 1e-9f : dx;
    const float sdy = (fabsf(dy) < 1e-9f) ? 1e-9f : dy;
    const float sdz = (fabsf(dz) < 1e-9f) ? 1e-9f : dz;
    const float t1x = (-RADIUS - ox) / sdx, t2x = (RADIUS - ox) / sdx;
    const float t1y = (-RADIUS - oy) / sdy, t2y = (RADIUS - oy) / sdy;
    const float t1z = (-RADIUS - oz) / sdz, t2z = (RADIUS - oz) / sdz;
    const float tnear = fmaxf(fmaxf(fmaxf(fminf(t1x, t2x), fminf(t1y, t2y)), fminf(t1z, t2z)), 0.0f);
    const float tfar  = fminf(fminf(fmaxf(t1x, t2x), fmaxf(t1y, t2y)), fmaxf(t1z, t2z));

    const float dnorm = sqrtf(dx * dx + dy * dy + dz * dz);
    const float inv   = 1.0f / dnorm;
    const float ux = dx * inv, uy = dy * inv, uz = dz * inv;

    // real SH basis deg<=2 (matches reference constants/signs)
    float sh[9];
    sh[0] = 0.28209479177387814f;
    sh[1] = -0.4886025119029199f * uy;
    sh[2] =  0.4886025119029199f * uz;
    sh[3] = -0.4886025119029199f * ux;
    sh[4] =  1.0925484305920792f * ux * uy;
    sh[5] = -1.0925484305920792f * uy * uz;
    sh[6] =  0.31539156525252005f * (2.0f * uz * uz - ux * ux - uy * uy);
    sh[7] = -1.0925484305920792f * ux * uz;
    sh[8] =  0.5462742152960396f * (ux * ux - uy * uy);

    // ---- stage 2: fold SH into dictionary: atomsR[cell][atom] = (r,g,b,sigma) ----
    // 64 cells * 16 atoms * 4 comps = 4096 scalars; 256 threads * 16 iters
    float* ldsRf = reinterpret_cast<float*>(ldsR);
    #pragma unroll
    for (int k = 0; k < 16; ++k) {
        const int idx  = tid + (k << 8);       // 0..4095
        const int pair = idx >> 2;             // cell*16 + atom
        const int cp   = idx & 3;              // 0..2 = rgb channel, 3 = sigma
        const float* row = atoms + pair * DATA_DIM;
        float v;
        if (cp < 3) {
            const float* r = row + cp * 9;
            v = sh[0] * r[0] + sh[1] * r[1] + sh[2] * r[2]
              + sh[3] * r[3] + sh[4] * r[4] + sh[5] * r[5]
              + sh[6] * r[6] + sh[7] * r[7] + sh[8] * r[8];
        } else {
            v = row[27];
        }
        const int cell = pair >> 4;
        const int atom = pair & 15;
        ldsRf[cell * (LDS_STRIDE * 4) + atom * 4 + cp] = v;
    }
    __syncthreads();

    // ---- stage 3: one sample per thread ----
    float alpha = 0.0f, tm = 0.0f;
    float pr = 0.0f, pg = 0.0f, pb = 0.0f;   // pre-sigmoid rgb

    if (tid < N_INTR) {
        const float ta = tnear + (float)tid * STEPF;
        const float tb = tnear + (float)(tid + 1) * STEPF;
        tm = 0.5f * (ta + tb);
        const float delta = (tb - ta) * dnorm;
        const bool mask = (tm < tfar) && (tfar > tnear);

        const float px = ox + dx * tm, py = oy + dy * tm, pz = oz + dz * tm;
        const float p01x = fminf(fmaxf((px + RADIUS) / (2.0f * RADIUS), 0.0f), 0.999999f);
        const float p01y = fminf(fmaxf((py + RADIUS) / (2.0f * RADIUS), 0.0f), 0.999999f);
        const float p01z = fminf(fmaxf((pz + RADIUS) / (2.0f * RADIUS), 0.0f), 0.999999f);

        // coarse trilinear -> 16 atom coefficients
        const float ccx = p01x * (COARSE - 1), ccy = p01y * (COARSE - 1), ccz = p01z * (COARSE - 1);
        const float fcx = ccx - floorf(ccx), fcy = ccy - floorf(ccy), fcz = ccz - floorf(ccz);
        int i0x = min(max((int)floorf(ccx), 0), COARSE - 1), i1x = min(i0x + 1, COARSE - 1);
        int i0y = min(max((int)floorf(ccy), 0), COARSE - 1), i1y = min(i0y + 1, COARSE - 1);
        int i0z = min(max((int)floorf(ccz), 0), COARSE - 1), i1z = min(i0z + 1, COARSE - 1);

        float cf[16];
        #pragma unroll
        for (int a = 0; a < 16; ++a) cf[a] = 0.0f;
        #pragma unroll
        for (int cn = 0; cn < 8; ++cn) {
            const int   ix = (cn & 4) ? i1x : i0x;
            const int   iy = (cn & 2) ? i1y : i0y;
            const int   iz = (cn & 1) ? i1z : i0z;
            const float wx = (cn & 4) ? fcx : 1.0f - fcx;
            const float wy = (cn & 2) ? fcy : 1.0f - fcy;
            const float wz = (cn & 1) ? fcz : 1.0f - fcz;
            const float w  = wx * wy * wz;
            const float4* g = reinterpret_cast<const float4*>(cgrid)
                              + ((((ix << 4) | iy) << 4) | iz) * 4;
            const float4 g0 = g[0], g1 = g[1], g2 = g[2], g3 = g[3];
            cf[0]  += w * g0.x; cf[1]  += w * g0.y; cf[2]  += w * g0.z; cf[3]  += w * g0.w;
            cf[4]  += w * g1.x; cf[5]  += w * g1.y; cf[6]  += w * g1.z; cf[7]  += w * g1.w;
            cf[8]  += w * g2.x; cf[9]  += w * g2.y; cf[10] += w * g2.z; cf[11] += w * g2.w;
            cf[12] += w * g3.x; cf[13] += w * g3.y; cf[14] += w * g3.z; cf[15] += w * g3.w;
        }

        // fine-local coordinate inside coarse voxel
        const float pfx = p01x * COARSE, pfy = p01y * COARSE, pfz = p01z * COARSE;
        const float lfx = (pfx - floorf(pfx)) * (FINE - 1);
        const float lfy = (pfy - floorf(pfy)) * (FINE - 1);
        const float lfz = (pfz - floorf(pfz)) * (FINE - 1);
        const float ffx = lfx - floorf(lfx), ffy = lfy - floorf(lfy), ffz = lfz - floorf(lfz);
        int j0x = min(max((int)floorf(lfx), 0), FINE - 1), j1x = min(j0x + 1, FINE - 1);
        int j0y = min(max((int)floorf(lfy), 0), FINE - 1), j1y = min(j0y + 1, FINE - 1);
        int j0z = min(max((int)floorf(lfz), 0), FINE - 1), j1z = min(j0z + 1, FINE - 1);

        int   cb[8];
        float wf[8];
        #pragma unroll
        for (int c = 0; c < 8; ++c) {
            const int   jx = (c & 4) ? j1x : j0x;
            const int   jy = (c & 2) ? j1y : j0y;
            const int   jz = (c & 1) ? j1z : j0z;
            const float wx = (c & 4) ? ffx : 1.0f - ffx;
            const float wy = (c & 2) ? ffy : 1.0f - ffy;
            const float wz = (c & 1) ? ffz : 1.0f - ffz;
            wf[c] = wx * wy * wz;
            cb[c] = (((jx << 2) | jy) << 2 | jz) * LDS_STRIDE;
        }

        // out4 = sum_a cf[a] * (sum_c wf[c] * atomsR[cell_c][a])
        float o4x = 0.0f, o4y = 0.0f, o4z = 0.0f, o4w = 0.0f;
        #pragma unroll
        for (int a = 0; a < 16; ++a) {
            float tx = 0.0f, ty = 0.0f, tz = 0.0f, tw = 0.0f;
            #pragma unroll
            for (int c = 0; c < 8; ++c) {
                const float4 v = ldsR[cb[c] + a];
                tx += wf[c] * v.x; ty += wf[c] * v.y;
                tz += wf[c] * v.z; tw += wf[c] * v.w;
            }
            o4x += cf[a] * tx; o4y += cf[a] * ty;
            o4z += cf[a] * tz; o4w += cf[a] * tw;
        }

        float sigma = fmaxf(o4w, 0.0f);
        if (!mask) sigma = 0.0f;
        alpha = 1.0f - expf(-sigma * delta);
        pr = o4x; pg = o4y; pb = o4z;

        // alpha output: [4B .. 4B + B*N)
        out[4 * gridDim.x + ray * N_INTR + tid] = alpha;
    }

    // ---- stage 4: exclusive cumprod scan of (1 - alpha + 1e-10) ----
    scanbuf[tid] = (tid < N_INTR) ? (1.0f - alpha + 1e-10f) : 1.0f;
    __syncthreads();
    #pragma unroll
    for (int off = 1; off < 256; off <<= 1) {
        const float a_ = scanbuf[tid];
        const float b_ = (tid >= off) ? scanbuf[tid - off] : 1.0f;
        __syncthreads();
        scanbuf[tid] = a_ * b_;
        __syncthreads();
    }
    const float trans = (tid == 0) ? 1.0f : scanbuf[tid - 1];
    const float w = alpha * trans;   // alpha==0 for tid>=N_INTR -> w==0

    // ---- stage 5: reductions ----
    float v0 = w * sigmoidf_(pr);
    float v1 = w * sigmoidf_(pg);
    float v2 = w * sigmoidf_(pb);
    float v3 = w * tm;
    float v4 = w;
    #pragma unroll
    for (int off = 32; off >= 1; off >>= 1) {
        v0 += __shfl_down(v0, off);
        v1 += __shfl_down(v1, off);
        v2 += __shfl_down(v2, off);
        v3 += __shfl_down(v3, off);
        v4 += __shfl_down(v4, off);
    }
    const int wid  = tid >> 6;
    const int lane = tid & 63;
    if (lane == 0) {
        partials[wid * 5 + 0] = v0; partials[wid * 5 + 1] = v1;
        partials[wid * 5 + 2] = v2; partials[wid * 5 + 3] = v3;
        partials[wid * 5 + 4] = v4;
    }
    __syncthreads();
    if (tid == 0) {
        float s0 = 0.0f, s1 = 0.0f, s2 = 0.0f, s3 = 0.0f, s4 = 0.0f;
        #pragma unroll
        for (int q = 0; q < 4; ++q) {
            s0 += partials[q * 5 + 0]; s1 += partials[q * 5 + 1];
            s2 += partials[q * 5 + 2]; s3 += partials[q * 5 + 3];
            s4 += partials[q * 5 + 4];
        }
        const float bg = 1.0f - s4;
        out[ray * 3 + 0] = s0 + bg;
        out[ray * 3 + 1] = s1 + bg;
        out[ray * 3 + 2] = s2 + bg;
        out[3 * gridDim.x + ray] = s3;                    // depth
        if (ray == 0)
            out[4 * gridDim.x + gridDim.x * N_INTR] = 0.0f;  // trailing scalar
    }
}

extern "C" void kernel_launch(void* const* d_in, const int* in_sizes, int n_in,
                              void* d_out, int out_size, void* d_ws, size_t ws_size,
                              hipStream_t stream)
{
    const float* rays_o = (const float*)d_in[0];
    const float* rays_d = (const float*)d_in[1];
    const float* cgrid  = (const float*)d_in[2];
    const float* atoms  = (const float*)d_in[3];
    float* out = (float*)d_out;

    const int n_rays = in_sizes[0] / 3;   // 1024
    plenoxel_fwd<<<n_rays, 256, 0, stream>>>(rays_o, rays_d, cgrid, atoms, out, n_rays);
}

// Round 2
// 326.753 us; speedup vs baseline: 1.0163x; 1.0163x over previous
//
#include <hip/hip_runtime.h>
#include <math.h>

#define RADIUS    1.3f
#define COARSE    16
#define FINE      4
#define NUM_ATOMS 16
#define DATA_DIM  28
#define N_INTR    217
#define STEPF     0.020634920634920634f

#define CELLS      64            // 4*4*4 fine cells
#define LDS_STRIDE 17            // float4 per cell: 16 atoms + 1 pad
#define RAYS_PB    4             // rays per block

__device__ __forceinline__ float sigmoidf_(float x) {
    return 1.0f / (1.0f + expf(-x));
}

__global__ __launch_bounds__(1024, 4)
void plenoxel_fwd(const float* __restrict__ rays_o,
                  const float* __restrict__ rays_d,
                  const float* __restrict__ cgrid,
                  const float* __restrict__ atoms,
                  float* __restrict__ out,
                  int n_rays)
{
    __shared__ float4 ldsR[RAYS_PB][CELLS * LDS_STRIDE]; // 4*17408 B folded dicts
    __shared__ float  scanbuf[1024];
    __shared__ float  rayp[RAYS_PB][20];                 // per-ray params
    __shared__ float  partials[16][5];

    const int tid = threadIdx.x;

    // ---- stage 0: per-ray setup (threads 0..3, one ray each) ----
    if (tid < RAYS_PB) {
        const int ray = blockIdx.x * RAYS_PB + tid;
        if (ray < n_rays) {
            const float ox = rays_o[ray * 3 + 0], oy = rays_o[ray * 3 + 1], oz = rays_o[ray * 3 + 2];
            const float dx = rays_d[ray * 3 + 0], dy = rays_d[ray * 3 + 1], dz = rays_d[ray * 3 + 2];
            const float sdx = (fabsf(dx) < 1e-9f) ? 1e-9f : dx;
            const float sdy = (fabsf(dy) < 1e-9f) ? 1e-9f : dy;
            const float sdz = (fabsf(dz) < 1e-9f) ? 1e-9f : dz;
            const float t1x = (-RADIUS - ox) / sdx, t2x = (RADIUS - ox) / sdx;
            const float t1y = (-RADIUS - oy) / sdy, t2y = (RADIUS - oy) / sdy;
            const float t1z = (-RADIUS - oz) / sdz, t2z = (RADIUS - oz) / sdz;
            const float tnear = fmaxf(fmaxf(fmaxf(fminf(t1x, t2x), fminf(t1y, t2y)), fminf(t1z, t2z)), 0.0f);
            const float tfar  = fminf(fminf(fmaxf(t1x, t2x), fmaxf(t1y, t2y)), fmaxf(t1z, t2z));
            const float dnorm = sqrtf(dx * dx + dy * dy + dz * dz);
            const float inv   = 1.0f / dnorm;
            const float ux = dx * inv, uy = dy * inv, uz = dz * inv;

            float* rp = rayp[tid];
            rp[0] = ox; rp[1] = oy; rp[2] = oz;
            rp[3] = dx; rp[4] = dy; rp[5] = dz;
            rp[6] = tnear; rp[7] = tfar; rp[8] = dnorm;
            rp[9]  = 0.28209479177387814f;
            rp[10] = -0.4886025119029199f * uy;
            rp[11] =  0.4886025119029199f * uz;
            rp[12] = -0.4886025119029199f * ux;
            rp[13] =  1.0925484305920792f * ux * uy;
            rp[14] = -1.0925484305920792f * uy * uz;
            rp[15] =  0.31539156525252005f * (2.0f * uz * uz - ux * ux - uy * uy);
            rp[16] = -1.0925484305920792f * ux * uz;
            rp[17] =  0.5462742152960396f * (ux * ux - uy * uy);
        }
    }
    __syncthreads();

    // ---- stage A: fold SH into dictionary, atoms read ONCE per block ----
    // 1024 rows (cell,atom); thread tid owns row tid. Row = 28 floats = 7 float4.
    {
        const float4* arow = reinterpret_cast<const float4*>(atoms) + tid * 7;
        const float4 a0 = arow[0], a1 = arow[1], a2 = arow[2], a3 = arow[3];
        const float4 a4 = arow[4], a5 = arow[5], a6 = arow[6];
        const float f[28] = { a0.x, a0.y, a0.z, a0.w, a1.x, a1.y, a1.z, a1.w,
                              a2.x, a2.y, a2.z, a2.w, a3.x, a3.y, a3.z, a3.w,
                              a4.x, a4.y, a4.z, a4.w, a5.x, a5.y, a5.z, a5.w,
                              a6.x, a6.y, a6.z, a6.w };
        const int cell = tid >> 4;
        const int atom = tid & 15;
        #pragma unroll
        for (int r = 0; r < RAYS_PB; ++r) {
            const float* sh = &rayp[r][9];
            float R = 0.0f, G = 0.0f, B = 0.0f;
            #pragma unroll
            for (int h = 0; h < 9; ++h) {
                const float s = sh[h];
                R += s * f[h];
                G += s * f[9 + h];
                B += s * f[18 + h];
            }
            ldsR[r][cell * LDS_STRIDE + atom] = make_float4(R, G, B, f[27]);
        }
    }
    __syncthreads();

    // ---- stage B: one sample per thread; group g = ray within block ----
    const int g   = tid >> 8;          // 0..3
    const int s   = tid & 255;         // sample id
    const int ray = blockIdx.x * RAYS_PB + g;
    const bool ray_ok = (ray < n_rays);

    const float* rp = rayp[g];
    const float ox = rp[0], oy = rp[1], oz = rp[2];
    const float dx = rp[3], dy = rp[4], dz = rp[5];
    const float tnear = rp[6], tfar = rp[7], dnorm = rp[8];

    float alpha = 0.0f, tm = 0.0f;
    float pr = 0.0f, pg = 0.0f, pb = 0.0f;

    if (ray_ok && s < N_INTR) {
        const float ta = tnear + (float)s * STEPF;
        const float tb = tnear + (float)(s + 1) * STEPF;
        tm = 0.5f * (ta + tb);
        const float delta = (tb - ta) * dnorm;
        const bool mask = (tm < tfar) && (tfar > tnear);

        const float px = ox + dx * tm, py = oy + dy * tm, pz = oz + dz * tm;
        const float p01x = fminf(fmaxf((px + RADIUS) / (2.0f * RADIUS), 0.0f), 0.999999f);
        const float p01y = fminf(fmaxf((py + RADIUS) / (2.0f * RADIUS), 0.0f), 0.999999f);
        const float p01z = fminf(fmaxf((pz + RADIUS) / (2.0f * RADIUS), 0.0f), 0.999999f);

        // coarse trilinear -> 16 atom coefficients
        const float ccx = p01x * (COARSE - 1), ccy = p01y * (COARSE - 1), ccz = p01z * (COARSE - 1);
        const float fcx = ccx - floorf(ccx), fcy = ccy - floorf(ccy), fcz = ccz - floorf(ccz);
        int i0x = min(max((int)floorf(ccx), 0), COARSE - 1), i1x = min(i0x + 1, COARSE - 1);
        int i0y = min(max((int)floorf(ccy), 0), COARSE - 1), i1y = min(i0y + 1, COARSE - 1);
        int i0z = min(max((int)floorf(ccz), 0), COARSE - 1), i1z = min(i0z + 1, COARSE - 1);

        float cf[16];
        #pragma unroll
        for (int a = 0; a < 16; ++a) cf[a] = 0.0f;
        #pragma unroll
        for (int cn = 0; cn < 8; ++cn) {
            const int   ix = (cn & 4) ? i1x : i0x;
            const int   iy = (cn & 2) ? i1y : i0y;
            const int   iz = (cn & 1) ? i1z : i0z;
            const float wx = (cn & 4) ? fcx : 1.0f - fcx;
            const float wy = (cn & 2) ? fcy : 1.0f - fcy;
            const float wz = (cn & 1) ? fcz : 1.0f - fcz;
            const float w  = wx * wy * wz;
            const float4* gp = reinterpret_cast<const float4*>(cgrid)
                               + ((((ix << 4) | iy) << 4) | iz) * 4;
            const float4 g0 = gp[0], g1 = gp[1], g2 = gp[2], g3 = gp[3];
            cf[0]  += w * g0.x; cf[1]  += w * g0.y; cf[2]  += w * g0.z; cf[3]  += w * g0.w;
            cf[4]  += w * g1.x; cf[5]  += w * g1.y; cf[6]  += w * g1.z; cf[7]  += w * g1.w;
            cf[8]  += w * g2.x; cf[9]  += w * g2.y; cf[10] += w * g2.z; cf[11] += w * g2.w;
            cf[12] += w * g3.x; cf[13] += w * g3.y; cf[14] += w * g3.z; cf[15] += w * g3.w;
        }

        // fine-local trilinear setup
        const float pfx = p01x * COARSE, pfy = p01y * COARSE, pfz = p01z * COARSE;
        const float lfx = (pfx - floorf(pfx)) * (FINE - 1);
        const float lfy = (pfy - floorf(pfy)) * (FINE - 1);
        const float lfz = (pfz - floorf(pfz)) * (FINE - 1);
        const float ffx = lfx - floorf(lfx), ffy = lfy - floorf(lfy), ffz = lfz - floorf(lfz);
        int j0x = min(max((int)floorf(lfx), 0), FINE - 1), j1x = min(j0x + 1, FINE - 1);
        int j0y = min(max((int)floorf(lfy), 0), FINE - 1), j1y = min(j0y + 1, FINE - 1);
        int j0z = min(max((int)floorf(lfz), 0), FINE - 1), j1z = min(j0z + 1, FINE - 1);

        int   cb[8];
        float wf[8];
        #pragma unroll
        for (int c = 0; c < 8; ++c) {
            const int   jx = (c & 4) ? j1x : j0x;
            const int   jy = (c & 2) ? j1y : j0y;
            const int   jz = (c & 1) ? j1z : j0z;
            const float wx = (c & 4) ? ffx : 1.0f - ffx;
            const float wy = (c & 2) ? ffy : 1.0f - ffy;
            const float wz = (c & 1) ? ffz : 1.0f - ffz;
            wf[c] = wx * wy * wz;
            cb[c] = (((jx << 2) | jy) << 2 | jz) * LDS_STRIDE;
        }

        const float4* dict = ldsR[g];
        float o4x = 0.0f, o4y = 0.0f, o4z = 0.0f, o4w = 0.0f;
        #pragma unroll
        for (int a = 0; a < 16; ++a) {
            float tx = 0.0f, ty = 0.0f, tz = 0.0f, tw = 0.0f;
            #pragma unroll
            for (int c = 0; c < 8; ++c) {
                const float4 v = dict[cb[c] + a];
                tx += wf[c] * v.x; ty += wf[c] * v.y;
                tz += wf[c] * v.z; tw += wf[c] * v.w;
            }
            o4x += cf[a] * tx; o4y += cf[a] * ty;
            o4z += cf[a] * tz; o4w += cf[a] * tw;
        }

        float sigma = fmaxf(o4w, 0.0f);
        if (!mask) sigma = 0.0f;
        alpha = 1.0f - expf(-sigma * delta);
        pr = o4x; pg = o4y; pb = o4z;

        out[4 * n_rays + ray * N_INTR + s] = alpha;
    }

    // ---- stage C: per-group exclusive cumprod scan (block-uniform barriers) ----
    scanbuf[tid] = (s < N_INTR) ? (1.0f - alpha + 1e-10f) : 1.0f;
    __syncthreads();
    #pragma unroll
    for (int off = 1; off < 256; off <<= 1) {
        const float a_ = scanbuf[tid];
        const float b_ = (s >= off) ? scanbuf[tid - off] : 1.0f;
        __syncthreads();
        scanbuf[tid] = a_ * b_;
        __syncthreads();
    }
    const float trans = (s == 0) ? 1.0f : scanbuf[tid - 1];
    const float w = alpha * trans;

    // ---- stage D: reductions (per 64-lane wave, then per group) ----
    float v0 = w * sigmoidf_(pr);
    float v1 = w * sigmoidf_(pg);
    float v2 = w * sigmoidf_(pb);
    float v3 = w * tm;
    float v4 = w;
    #pragma unroll
    for (int off = 32; off >= 1; off >>= 1) {
        v0 += __shfl_down(v0, off);
        v1 += __shfl_down(v1, off);
        v2 += __shfl_down(v2, off);
        v3 += __shfl_down(v3, off);
        v4 += __shfl_down(v4, off);
    }
    const int wid = tid >> 6;   // 0..15, 4 waves per group
    if ((tid & 63) == 0) {
        partials[wid][0] = v0; partials[wid][1] = v1;
        partials[wid][2] = v2; partials[wid][3] = v3;
        partials[wid][4] = v4;
    }
    __syncthreads();
    if (s == 0 && ray_ok) {
        float s0 = 0.0f, s1 = 0.0f, s2 = 0.0f, s3 = 0.0f, s4 = 0.0f;
        #pragma unroll
        for (int q = 0; q < 4; ++q) {
            s0 += partials[g * 4 + q][0]; s1 += partials[g * 4 + q][1];
            s2 += partials[g * 4 + q][2]; s3 += partials[g * 4 + q][3];
            s4 += partials[g * 4 + q][4];
        }
        const float bg = 1.0f - s4;
        out[ray * 3 + 0] = s0 + bg;
        out[ray * 3 + 1] = s1 + bg;
        out[ray * 3 + 2] = s2 + bg;
        out[3 * n_rays + ray] = s3;                        // depth
        if (ray == 0)
            out[4 * n_rays + n_rays * N_INTR] = 0.0f;      // trailing scalar
    }
}

extern "C" void kernel_launch(void* const* d_in, const int* in_sizes, int n_in,
                              void* d_out, int out_size, void* d_ws, size_t ws_size,
                              hipStream_t stream)
{
    const float* rays_o = (const float*)d_in[0];
    const float* rays_d = (const float*)d_in[1];
    const float* cgrid  = (const float*)d_in[2];
    const float* atoms  = (const float*)d_in[3];
    float* out = (float*)d_out;

    const int n_rays = in_sizes[0] / 3;                   // 1024
    const int blocks = (n_rays + RAYS_PB - 1) / RAYS_PB;  // 256
    plenoxel_fwd<<<blocks, 1024, 0, stream>>>(rays_o, rays_d, cgrid, atoms, out, n_rays);
}

// Round 6
// 266.102 us; speedup vs baseline: 1.2479x; 1.2279x over previous
//
#include <hip/hip_runtime.h>
#include <math.h>

#define RADIUS    1.3f
#define COARSE    16
#define FINE      4
#define NUM_ATOMS 16
#define DATA_DIM  28
#define N_INTR    217
#define STEPF     0.020634920634920634f

#define CELLS      64            // 4*4*4 fine cells
#define LDS_STRIDE 17            // float4 per cell: 16 atoms + 1 pad
#define RAYS_PB    4             // rays per block

__device__ __forceinline__ float sigmoidf_(float x) {
    return 1.0f / (1.0f + expf(-x));
}

__global__ __launch_bounds__(1024, 4)
void plenoxel_fwd(const float* __restrict__ rays_o,
                  const float* __restrict__ rays_d,
                  const float* __restrict__ cgrid,
                  const float* __restrict__ atoms,
                  float* __restrict__ out,
                  int n_rays)
{
    __shared__ float4 ldsR[RAYS_PB][CELLS * LDS_STRIDE]; // 4*17408 B folded dicts
    __shared__ float  rayp[RAYS_PB][20];                 // per-ray params
    __shared__ float  wtot[16];                          // per-wave scan totals
    __shared__ float  partials[16][5];

    const int tid = threadIdx.x;

    // ---- stage 0: per-ray setup (threads 0..3, one ray each) ----
    if (tid < RAYS_PB) {
        const int ray = blockIdx.x * RAYS_PB + tid;
        if (ray < n_rays) {
            const float ox = rays_o[ray * 3 + 0], oy = rays_o[ray * 3 + 1], oz = rays_o[ray * 3 + 2];
            const float dx = rays_d[ray * 3 + 0], dy = rays_d[ray * 3 + 1], dz = rays_d[ray * 3 + 2];
            const float sdx = (fabsf(dx) < 1e-9f) ? 1e-9f : dx;
            const float sdy = (fabsf(dy) < 1e-9f) ? 1e-9f : dy;
            const float sdz = (fabsf(dz) < 1e-9f) ? 1e-9f : dz;
            const float t1x = (-RADIUS - ox) / sdx, t2x = (RADIUS - ox) / sdx;
            const float t1y = (-RADIUS - oy) / sdy, t2y = (RADIUS - oy) / sdy;
            const float t1z = (-RADIUS - oz) / sdz, t2z = (RADIUS - oz) / sdz;
            const float tnear = fmaxf(fmaxf(fmaxf(fminf(t1x, t2x), fminf(t1y, t2y)), fminf(t1z, t2z)), 0.0f);
            const float tfar  = fminf(fminf(fmaxf(t1x, t2x), fmaxf(t1y, t2y)), fmaxf(t1z, t2z));
            const float dnorm = sqrtf(dx * dx + dy * dy + dz * dz);
            const float inv   = 1.0f / dnorm;
            const float ux = dx * inv, uy = dy * inv, uz = dz * inv;

            float* rp = rayp[tid];
            rp[0] = ox; rp[1] = oy; rp[2] = oz;
            rp[3] = dx; rp[4] = dy; rp[5] = dz;
            rp[6] = tnear; rp[7] = tfar; rp[8] = dnorm;
            rp[9]  = 0.28209479177387814f;
            rp[10] = -0.4886025119029199f * uy;
            rp[11] =  0.4886025119029199f * uz;
            rp[12] = -0.4886025119029199f * ux;
            rp[13] =  1.0925484305920792f * ux * uy;
            rp[14] = -1.0925484305920792f * uy * uz;
            rp[15] =  0.31539156525252005f * (2.0f * uz * uz - ux * ux - uy * uy);
            rp[16] = -1.0925484305920792f * ux * uz;
            rp[17] =  0.5462742152960396f * (ux * ux - uy * uy);
        }
    }
    __syncthreads();

    // ---- stage A: fold SH into dictionary, atoms read ONCE per block ----
    {
        const float4* arow = reinterpret_cast<const float4*>(atoms) + tid * 7;
        const float4 a0 = arow[0], a1 = arow[1], a2 = arow[2], a3 = arow[3];
        const float4 a4 = arow[4], a5 = arow[5], a6 = arow[6];
        const float f[28] = { a0.x, a0.y, a0.z, a0.w, a1.x, a1.y, a1.z, a1.w,
                              a2.x, a2.y, a2.z, a2.w, a3.x, a3.y, a3.z, a3.w,
                              a4.x, a4.y, a4.z, a4.w, a5.x, a5.y, a5.z, a5.w,
                              a6.x, a6.y, a6.z, a6.w };
        const int cell = tid >> 4;
        const int atom = tid & 15;
        #pragma unroll
        for (int r = 0; r < RAYS_PB; ++r) {
            const float* sh = &rayp[r][9];
            float R = 0.0f, G = 0.0f, B = 0.0f;
            #pragma unroll
            for (int h = 0; h < 9; ++h) {
                const float s_ = sh[h];
                R += s_ * f[h];
                G += s_ * f[9 + h];
                B += s_ * f[18 + h];
            }
            ldsR[r][cell * LDS_STRIDE + atom] = make_float4(R, G, B, f[27]);
        }
    }
    __syncthreads();

    // ---- stage B: one sample per thread; group g = ray within block ----
    const int g   = tid >> 8;          // 0..3
    const int s   = tid & 255;         // sample id
    const int ray = blockIdx.x * RAYS_PB + g;
    const bool ray_ok = (ray < n_rays);

    const float* rp = rayp[g];
    const float tnear = rp[6], tfar = rp[7], dnorm = rp[8];

    float alpha = 0.0f, tm = 0.0f;
    float pr = 0.0f, pg = 0.0f, pb = 0.0f;
    float v = 1.0f;                    // scan input (1 - alpha + 1e-10)

    if (ray_ok && s < N_INTR) {
        tm = tnear + ((float)s + 0.5f) * STEPF;
        const bool mask = (tm < tfar) && (tfar > tnear);

        if (mask) {
            const float ox = rp[0], oy = rp[1], oz = rp[2];
            const float dx = rp[3], dy = rp[4], dz = rp[5];
            const float delta = STEPF * dnorm;

            const float px = ox + dx * tm, py = oy + dy * tm, pz = oz + dz * tm;
            const float p01x = fminf(fmaxf((px + RADIUS) / (2.0f * RADIUS), 0.0f), 0.999999f);
            const float p01y = fminf(fmaxf((py + RADIUS) / (2.0f * RADIUS), 0.0f), 0.999999f);
            const float p01z = fminf(fmaxf((pz + RADIUS) / (2.0f * RADIUS), 0.0f), 0.999999f);

            // coarse trilinear -> 16 atom coefficients
            const float ccx = p01x * (COARSE - 1), ccy = p01y * (COARSE - 1), ccz = p01z * (COARSE - 1);
            const float fcx = ccx - floorf(ccx), fcy = ccy - floorf(ccy), fcz = ccz - floorf(ccz);
            int i0x = min(max((int)floorf(ccx), 0), COARSE - 1), i1x = min(i0x + 1, COARSE - 1);
            int i0y = min(max((int)floorf(ccy), 0), COARSE - 1), i1y = min(i0y + 1, COARSE - 1);
            int i0z = min(max((int)floorf(ccz), 0), COARSE - 1), i1z = min(i0z + 1, COARSE - 1);

            float cf[16];
            #pragma unroll
            for (int a = 0; a < 16; ++a) cf[a] = 0.0f;
            #pragma unroll
            for (int cn = 0; cn < 8; ++cn) {
                const int   ix = (cn & 4) ? i1x : i0x;
                const int   iy = (cn & 2) ? i1y : i0y;
                const int   iz = (cn & 1) ? i1z : i0z;
                const float wx = (cn & 4) ? fcx : 1.0f - fcx;
                const float wy = (cn & 2) ? fcy : 1.0f - fcy;
                const float wz = (cn & 1) ? fcz : 1.0f - fcz;
                const float w  = wx * wy * wz;
                const float4* gp = reinterpret_cast<const float4*>(cgrid)
                                   + ((((ix << 4) | iy) << 4) | iz) * 4;
                const float4 g0 = gp[0], g1 = gp[1], g2 = gp[2], g3 = gp[3];
                cf[0]  += w * g0.x; cf[1]  += w * g0.y; cf[2]  += w * g0.z; cf[3]  += w * g0.w;
                cf[4]  += w * g1.x; cf[5]  += w * g1.y; cf[6]  += w * g1.z; cf[7]  += w * g1.w;
                cf[8]  += w * g2.x; cf[9]  += w * g2.y; cf[10] += w * g2.z; cf[11] += w * g2.w;
                cf[12] += w * g3.x; cf[13] += w * g3.y; cf[14] += w * g3.z; cf[15] += w * g3.w;
            }

            // fine-local trilinear setup
            const float pfx = p01x * COARSE, pfy = p01y * COARSE, pfz = p01z * COARSE;
            const float lfx = (pfx - floorf(pfx)) * (FINE - 1);
            const float lfy = (pfy - floorf(pfy)) * (FINE - 1);
            const float lfz = (pfz - floorf(pfz)) * (FINE - 1);
            const float ffx = lfx - floorf(lfx), ffy = lfy - floorf(lfy), ffz = lfz - floorf(lfz);
            int j0x = min(max((int)floorf(lfx), 0), FINE - 1), j1x = min(j0x + 1, FINE - 1);
            int j0y = min(max((int)floorf(lfy), 0), FINE - 1), j1y = min(j0y + 1, FINE - 1);
            int j0z = min(max((int)floorf(lfz), 0), FINE - 1), j1z = min(j0z + 1, FINE - 1);

            int   cb[8];
            float wf[8];
            #pragma unroll
            for (int c = 0; c < 8; ++c) {
                const int   jx = (c & 4) ? j1x : j0x;
                const int   jy = (c & 2) ? j1y : j0y;
                const int   jz = (c & 1) ? j1z : j0z;
                const float wx = (c & 4) ? ffx : 1.0f - ffx;
                const float wy = (c & 2) ? ffy : 1.0f - ffy;
                const float wz = (c & 1) ? ffz : 1.0f - ffz;
                wf[c] = wx * wy * wz;
                cb[c] = (((jx << 2) | jy) << 2 | jz) * LDS_STRIDE;
            }

            const float4* dict = ldsR[g];
            float o4x = 0.0f, o4y = 0.0f, o4z = 0.0f, o4w = 0.0f;
            #pragma unroll
            for (int a = 0; a < 16; ++a) {
                float tx = 0.0f, ty = 0.0f, tz = 0.0f, tw = 0.0f;
                #pragma unroll
                for (int c = 0; c < 8; ++c) {
                    const float4 vv = dict[cb[c] + a];
                    tx += wf[c] * vv.x; ty += wf[c] * vv.y;
                    tz += wf[c] * vv.z; tw += wf[c] * vv.w;
                }
                o4x += cf[a] * tx; o4y += cf[a] * ty;
                o4z += cf[a] * tz; o4w += cf[a] * tw;
            }

            const float sigma = fmaxf(o4w, 0.0f);
            alpha = 1.0f - expf(-sigma * delta);
            pr = o4x; pg = o4y; pb = o4z;
        }

        out[4 * n_rays + ray * N_INTR + s] = alpha;
        v = 1.0f - alpha + 1e-10f;
    }

    // ---- stage C: cumprod scan — wave shuffles + one barrier ----
    const int lane = tid & 63;
    float incl = v;
    #pragma unroll
    for (int off = 1; off < 64; off <<= 1) {
        const float t = __shfl_up(incl, off);
        if (lane >= off) incl *= t;
    }
    const int wid = tid >> 6;          // 0..15 (4 waves per group)
    if (lane == 63) wtot[wid] = incl;
    __syncthreads();
    float prefix = 1.0f;
    {
        const int w0  = g * 4;
        const int myw = wid & 3;
        #pragma unroll
        for (int q = 0; q < 3; ++q)
            if (q < myw) prefix *= wtot[w0 + q];
    }
    float excl = __shfl_up(incl, 1);
    if (lane == 0) excl = 1.0f;
    const float trans = prefix * excl;
    const float w = alpha * trans;     // alpha==0 for invalid/masked -> w==0

    // ---- stage D: reductions (per 64-lane wave, then per group) ----
    float v0 = w * sigmoidf_(pr);
    float v1 = w * sigmoidf_(pg);
    float v2 = w * sigmoidf_(pb);
    float v3 = w * tm;
    float v4 = w;
    #pragma unroll
    for (int off = 32; off >= 1; off >>= 1) {
        v0 += __shfl_down(v0, off);
        v1 += __shfl_down(v1, off);
        v2 += __shfl_down(v2, off);
        v3 += __shfl_down(v3, off);
        v4 += __shfl_down(v4, off);
    }
    if (lane == 0) {
        partials[wid][0] = v0; partials[wid][1] = v1;
        partials[wid][2] = v2; partials[wid][3] = v3;
        partials[wid][4] = v4;
    }
    __syncthreads();
    if (s == 0 && ray_ok) {
        float s0 = 0.0f, s1 = 0.0f, s2 = 0.0f, s3 = 0.0f, s4 = 0.0f;
        #pragma unroll
        for (int q = 0; q < 4; ++q) {
            s0 += partials[g * 4 + q][0]; s1 += partials[g * 4 + q][1];
            s2 += partials[g * 4 + q][2]; s3 += partials[g * 4 + q][3];
            s4 += partials[g * 4 + q][4];
        }
        const float bg = 1.0f - s4;
        out[ray * 3 + 0] = s0 + bg;
        out[ray * 3 + 1] = s1 + bg;
        out[ray * 3 + 2] = s2 + bg;
        out[3 * n_rays + ray] = s3;                        // depth
        if (ray == 0)
            out[4 * n_rays + n_rays * N_INTR] = 0.0f;      // trailing scalar
    }
}

extern "C" void kernel_launch(void* const* d_in, const int* in_sizes, int n_in,
                              void* d_out, int out_size, void* d_ws, size_t ws_size,
                              hipStream_t stream)
{
    const float* rays_o = (const float*)d_in[0];
    const float* rays_d = (const float*)d_in[1];
    const float* cgrid  = (const float*)d_in[2];
    const float* atoms  = (const float*)d_in[3];
    float* out = (float*)d_out;

    const int n_rays = in_sizes[0] / 3;                   // 1024
    const int blocks = (n_rays + RAYS_PB - 1) / RAYS_PB;  // 256
    plenoxel_fwd<<<blocks, 1024, 0, stream>>>(rays_o, rays_d, cgrid, atoms, out, n_rays);
}

// Round 8
// 196.285 us; speedup vs baseline: 1.6918x; 1.3557x over previous
//
#include <hip/hip_runtime.h>
#include <math.h>

#define RADIUS    1.3f
#define COARSE    16
#define FINE      4
#define NUM_ATOMS 16
#define DATA_DIM  28
#define N_INTR    217
#define STEPF     0.020634920634920634f

#define CELLS      64            // 4*4*4 fine cells
#define LDS_STRIDE 17            // float4 per cell: 16 atoms + 1 pad
#define RAYS_PB    2             // rays per block
#define NTHREADS   512

__device__ __forceinline__ float sigmoidf_(float x) {
    return 1.0f / (1.0f + expf(-x));
}

__global__ __launch_bounds__(NTHREADS)
void plenoxel_fwd(const float* __restrict__ rays_o,
                  const float* __restrict__ rays_d,
                  const float* __restrict__ cgrid,
                  const float* __restrict__ atoms,
                  float* __restrict__ out,
                  int n_rays)
{
    __shared__ float4 ldsR[RAYS_PB][CELLS * LDS_STRIDE]; // 2*17408 B folded dicts
    __shared__ float  rayp[RAYS_PB][20];                 // per-ray params
    __shared__ float  wtot[8];                           // per-wave scan totals
    __shared__ float  partials[8][5];

    const int tid = threadIdx.x;

    // ---- stage 0: per-ray setup (threads 0..1, one ray each) ----
    if (tid < RAYS_PB) {
        const int ray = blockIdx.x * RAYS_PB + tid;
        if (ray < n_rays) {
            const float ox = rays_o[ray * 3 + 0], oy = rays_o[ray * 3 + 1], oz = rays_o[ray * 3 + 2];
            const float dx = rays_d[ray * 3 + 0], dy = rays_d[ray * 3 + 1], dz = rays_d[ray * 3 + 2];
            const float sdx = (fabsf(dx) < 1e-9f) ? 1e-9f : dx;
            const float sdy = (fabsf(dy) < 1e-9f) ? 1e-9f : dy;
            const float sdz = (fabsf(dz) < 1e-9f) ? 1e-9f : dz;
            const float t1x = (-RADIUS - ox) / sdx, t2x = (RADIUS - ox) / sdx;
            const float t1y = (-RADIUS - oy) / sdy, t2y = (RADIUS - oy) / sdy;
            const float t1z = (-RADIUS - oz) / sdz, t2z = (RADIUS - oz) / sdz;
            const float tnear = fmaxf(fmaxf(fmaxf(fminf(t1x, t2x), fminf(t1y, t2y)), fminf(t1z, t2z)), 0.0f);
            const float tfar  = fminf(fminf(fmaxf(t1x, t2x), fmaxf(t1y, t2y)), fmaxf(t1z, t2z));
            const float dnorm = sqrtf(dx * dx + dy * dy + dz * dz);
            const float inv   = 1.0f / dnorm;
            const float ux = dx * inv, uy = dy * inv, uz = dz * inv;

            float* rp = rayp[tid];
            rp[0] = ox; rp[1] = oy; rp[2] = oz;
            rp[3] = dx; rp[4] = dy; rp[5] = dz;
            rp[6] = tnear; rp[7] = tfar; rp[8] = dnorm;
            rp[9]  = 0.28209479177387814f;
            rp[10] = -0.4886025119029199f * uy;
            rp[11] =  0.4886025119029199f * uz;
            rp[12] = -0.4886025119029199f * ux;
            rp[13] =  1.0925484305920792f * ux * uy;
            rp[14] = -1.0925484305920792f * uy * uz;
            rp[15] =  0.31539156525252005f * (2.0f * uz * uz - ux * ux - uy * uy);
            rp[16] = -1.0925484305920792f * ux * uz;
            rp[17] =  0.5462742152960396f * (ux * ux - uy * uy);
        }
    }
    __syncthreads();

    // ---- stage A: fold SH into dictionary; 1024 rows, 512 threads x 2 rows ----
    #pragma unroll
    for (int rr = 0; rr < 2; ++rr) {
        const int row = tid + rr * NTHREADS;
        const float4* arow = reinterpret_cast<const float4*>(atoms) + row * 7;
        const float4 a0 = arow[0], a1 = arow[1], a2 = arow[2], a3 = arow[3];
        const float4 a4 = arow[4], a5 = arow[5], a6 = arow[6];
        const float f[28] = { a0.x, a0.y, a0.z, a0.w, a1.x, a1.y, a1.z, a1.w,
                              a2.x, a2.y, a2.z, a2.w, a3.x, a3.y, a3.z, a3.w,
                              a4.x, a4.y, a4.z, a4.w, a5.x, a5.y, a5.z, a5.w,
                              a6.x, a6.y, a6.z, a6.w };
        const int cell = row >> 4;
        const int atom = row & 15;
        #pragma unroll
        for (int r = 0; r < RAYS_PB; ++r) {
            const float* sh = &rayp[r][9];
            float R = 0.0f, G = 0.0f, B = 0.0f;
            #pragma unroll
            for (int h = 0; h < 9; ++h) {
                const float s_ = sh[h];
                R += s_ * f[h];
                G += s_ * f[9 + h];
                B += s_ * f[18 + h];
            }
            ldsR[r][cell * LDS_STRIDE + atom] = make_float4(R, G, B, f[27]);
        }
    }
    __syncthreads();

    // ---- stage B: one sample per thread; group g = ray within block ----
    const int g   = tid >> 8;          // 0..1
    const int s   = tid & 255;         // sample id
    const int ray = blockIdx.x * RAYS_PB + g;
    const bool ray_ok = (ray < n_rays);

    const float* rp = rayp[g];
    const float tnear = rp[6], tfar = rp[7], dnorm = rp[8];

    float alpha = 0.0f, tm = 0.0f;
    float pr = 0.0f, pg = 0.0f, pb = 0.0f;
    float v = 1.0f;                    // scan input (1 - alpha + 1e-10)

    if (ray_ok && s < N_INTR) {
        tm = tnear + ((float)s + 0.5f) * STEPF;
        const bool mask = (tm < tfar) && (tfar > tnear);

        if (mask) {
            const float ox = rp[0], oy = rp[1], oz = rp[2];
            const float dx = rp[3], dy = rp[4], dz = rp[5];
            const float delta = STEPF * dnorm;

            const float px = ox + dx * tm, py = oy + dy * tm, pz = oz + dz * tm;
            const float p01x = fminf(fmaxf((px + RADIUS) / (2.0f * RADIUS), 0.0f), 0.999999f);
            const float p01y = fminf(fmaxf((py + RADIUS) / (2.0f * RADIUS), 0.0f), 0.999999f);
            const float p01z = fminf(fmaxf((pz + RADIUS) / (2.0f * RADIUS), 0.0f), 0.999999f);

            // coarse trilinear -> 16 atom coefficients.
            // Stage ALL 8 corners (32 float4) into registers first for max MLP.
            const float ccx = p01x * (COARSE - 1), ccy = p01y * (COARSE - 1), ccz = p01z * (COARSE - 1);
            const float fcx = ccx - floorf(ccx), fcy = ccy - floorf(ccy), fcz = ccz - floorf(ccz);
            int i0x = min(max((int)floorf(ccx), 0), COARSE - 1), i1x = min(i0x + 1, COARSE - 1);
            int i0y = min(max((int)floorf(ccy), 0), COARSE - 1), i1y = min(i0y + 1, COARSE - 1);
            int i0z = min(max((int)floorf(ccz), 0), COARSE - 1), i1z = min(i0z + 1, COARSE - 1);

            float4 gq[8][4];
            float  wcn[8];
            #pragma unroll
            for (int cn = 0; cn < 8; ++cn) {
                const int   ix = (cn & 4) ? i1x : i0x;
                const int   iy = (cn & 2) ? i1y : i0y;
                const int   iz = (cn & 1) ? i1z : i0z;
                const float wx = (cn & 4) ? fcx : 1.0f - fcx;
                const float wy = (cn & 2) ? fcy : 1.0f - fcy;
                const float wz = (cn & 1) ? fcz : 1.0f - fcz;
                wcn[cn] = wx * wy * wz;
                const float4* gp = reinterpret_cast<const float4*>(cgrid)
                                   + ((((ix << 4) | iy) << 4) | iz) * 4;
                gq[cn][0] = gp[0]; gq[cn][1] = gp[1];
                gq[cn][2] = gp[2]; gq[cn][3] = gp[3];
            }

            float cf[16];
            #pragma unroll
            for (int a = 0; a < 16; ++a) cf[a] = 0.0f;
            #pragma unroll
            for (int cn = 0; cn < 8; ++cn) {
                const float w = wcn[cn];
                #pragma unroll
                for (int k = 0; k < 4; ++k) {
                    const float4 gv = gq[cn][k];
                    cf[k * 4 + 0] += w * gv.x;
                    cf[k * 4 + 1] += w * gv.y;
                    cf[k * 4 + 2] += w * gv.z;
                    cf[k * 4 + 3] += w * gv.w;
                }
            }

            // fine-local trilinear setup
            const float pfx = p01x * COARSE, pfy = p01y * COARSE, pfz = p01z * COARSE;
            const float lfx = (pfx - floorf(pfx)) * (FINE - 1);
            const float lfy = (pfy - floorf(pfy)) * (FINE - 1);
            const float lfz = (pfz - floorf(pfz)) * (FINE - 1);
            const float ffx = lfx - floorf(lfx), ffy = lfy - floorf(lfy), ffz = lfz - floorf(lfz);
            int j0x = min(max((int)floorf(lfx), 0), FINE - 1), j1x = min(j0x + 1, FINE - 1);
            int j0y = min(max((int)floorf(lfy), 0), FINE - 1), j1y = min(j0y + 1, FINE - 1);
            int j0z = min(max((int)floorf(lfz), 0), FINE - 1), j1z = min(j0z + 1, FINE - 1);

            int   cb[8];
            float wf[8];
            #pragma unroll
            for (int c = 0; c < 8; ++c) {
                const int   jx = (c & 4) ? j1x : j0x;
                const int   jy = (c & 2) ? j1y : j0y;
                const int   jz = (c & 1) ? j1z : j0z;
                const float wx = (c & 4) ? ffx : 1.0f - ffx;
                const float wy = (c & 2) ? ffy : 1.0f - ffy;
                const float wz = (c & 1) ? ffz : 1.0f - ffz;
                wf[c] = wx * wy * wz;
                cb[c] = (((jx << 2) | jy) << 2 | jz) * LDS_STRIDE;
            }

            const float4* dict = ldsR[g];
            float o4x = 0.0f, o4y = 0.0f, o4z = 0.0f, o4w = 0.0f;
            #pragma unroll
            for (int a = 0; a < 16; ++a) {
                float tx = 0.0f, ty = 0.0f, tz = 0.0f, tw = 0.0f;
                #pragma unroll
                for (int c = 0; c < 8; ++c) {
                    const float4 vv = dict[cb[c] + a];
                    tx += wf[c] * vv.x; ty += wf[c] * vv.y;
                    tz += wf[c] * vv.z; tw += wf[c] * vv.w;
                }
                o4x += cf[a] * tx; o4y += cf[a] * ty;
                o4z += cf[a] * tz; o4w += cf[a] * tw;
            }

            const float sigma = fmaxf(o4w, 0.0f);
            alpha = 1.0f - expf(-sigma * delta);
            pr = o4x; pg = o4y; pb = o4z;
        }

        out[4 * n_rays + ray * N_INTR + s] = alpha;
        v = 1.0f - alpha + 1e-10f;
    }

    // ---- stage C: cumprod scan — wave shuffles + one barrier ----
    const int lane = tid & 63;
    float incl = v;
    #pragma unroll
    for (int off = 1; off < 64; off <<= 1) {
        const float t = __shfl_up(incl, off);
        if (lane >= off) incl *= t;
    }
    const int wid = tid >> 6;          // 0..7 (4 waves per group)
    if (lane == 63) wtot[wid] = incl;
    __syncthreads();
    float prefix = 1.0f;
    {
        const int w0  = g * 4;
        const int myw = wid & 3;
        #pragma unroll
        for (int q = 0; q < 3; ++q)
            if (q < myw) prefix *= wtot[w0 + q];
    }
    float excl = __shfl_up(incl, 1);
    if (lane == 0) excl = 1.0f;
    const float trans = prefix * excl;
    const float w = alpha * trans;     // alpha==0 for invalid/masked -> w==0

    // ---- stage D: reductions (per 64-lane wave, then per group) ----
    float v0 = w * sigmoidf_(pr);
    float v1 = w * sigmoidf_(pg);
    float v2 = w * sigmoidf_(pb);
    float v3 = w * tm;
    float v4 = w;
    #pragma unroll
    for (int off = 32; off >= 1; off >>= 1) {
        v0 += __shfl_down(v0, off);
        v1 += __shfl_down(v1, off);
        v2 += __shfl_down(v2, off);
        v3 += __shfl_down(v3, off);
        v4 += __shfl_down(v4, off);
    }
    if (lane == 0) {
        partials[wid][0] = v0; partials[wid][1] = v1;
        partials[wid][2] = v2; partials[wid][3] = v3;
        partials[wid][4] = v4;
    }
    __syncthreads();
    if (s == 0 && ray_ok) {
        float s0 = 0.0f, s1 = 0.0f, s2 = 0.0f, s3 = 0.0f, s4 = 0.0f;
        #pragma unroll
        for (int q = 0; q < 4; ++q) {
            s0 += partials[g * 4 + q][0]; s1 += partials[g * 4 + q][1];
            s2 += partials[g * 4 + q][2]; s3 += partials[g * 4 + q][3];
            s4 += partials[g * 4 + q][4];
        }
        const float bg = 1.0f - s4;
        out[ray * 3 + 0] = s0 + bg;
        out[ray * 3 + 1] = s1 + bg;
        out[ray * 3 + 2] = s2 + bg;
        out[3 * n_rays + ray] = s3;                        // depth
        if (ray == 0)
            out[4 * n_rays + n_rays * N_INTR] = 0.0f;      // trailing scalar
    }
}

extern "C" void kernel_launch(void* const* d_in, const int* in_sizes, int n_in,
                              void* d_out, int out_size, void* d_ws, size_t ws_size,
                              hipStream_t stream)
{
    const float* rays_o = (const float*)d_in[0];
    const float* rays_d = (const float*)d_in[1];
    const float* cgrid  = (const float*)d_in[2];
    const float* atoms  = (const float*)d_in[3];
    float* out = (float*)d_out;

    const int n_rays = in_sizes[0] / 3;                   // 1024
    const int blocks = (n_rays + RAYS_PB - 1) / RAYS_PB;  // 512
    plenoxel_fwd<<<blocks, NTHREADS, 0, stream>>>(rays_o, rays_d, cgrid, atoms, out, n_rays);
}

// Round 11
// 95.775 us; speedup vs baseline: 3.4671x; 2.0494x over previous
//
#include <hip/hip_runtime.h>
#include <math.h>

#define RADIUS    1.3f
#define COARSE    16
#define FINE      4
#define NUM_ATOMS 16
#define DATA_DIM  28
#define N_INTR    217
#define STEPF     0.020634920634920634f

#define CELLS      64            // 4*4*4 fine cells
#define LDS_STRIDE 17            // float4 per cell: 16 atoms + 1 pad
#define NTHREADS   256

__device__ __forceinline__ float sigmoidf_(float x) {
    return 1.0f / (1.0f + expf(-x));
}

__global__ __launch_bounds__(NTHREADS)
void plenoxel_fwd(const float* __restrict__ rays_o,
                  const float* __restrict__ rays_d,
                  const float* __restrict__ cgrid,
                  const float* __restrict__ atoms,
                  float* __restrict__ out,
                  int n_rays)
{
    __shared__ float4 ldsR[CELLS * LDS_STRIDE];   // 17408 B folded dict (1 ray)
    __shared__ float  wtot[4];                    // per-wave scan totals
    __shared__ float  partials[4][5];

    const int tid = threadIdx.x;
    const int ray = blockIdx.x;
    const int s   = tid;

    // ---- ray setup: redundant per thread (no barrier, no LDS round-trip) ----
    const float ox = rays_o[ray * 3 + 0], oy = rays_o[ray * 3 + 1], oz = rays_o[ray * 3 + 2];
    const float dx = rays_d[ray * 3 + 0], dy = rays_d[ray * 3 + 1], dz = rays_d[ray * 3 + 2];
    const float sdx = (fabsf(dx) < 1e-9f) ? 1e-9f : dx;
    const float sdy = (fabsf(dy) < 1e-9f) ? 1e-9f : dy;
    const float sdz = (fabsf(dz) < 1e-9f) ? 1e-9f : dz;
    const float t1x = (-RADIUS - ox) / sdx, t2x = (RADIUS - ox) / sdx;
    const float t1y = (-RADIUS - oy) / sdy, t2y = (RADIUS - oy) / sdy;
    const float t1z = (-RADIUS - oz) / sdz, t2z = (RADIUS - oz) / sdz;
    const float tnear = fmaxf(fmaxf(fmaxf(fminf(t1x, t2x), fminf(t1y, t2y)), fminf(t1z, t2z)), 0.0f);
    const float tfar  = fminf(fminf(fmaxf(t1x, t2x), fmaxf(t1y, t2y)), fmaxf(t1z, t2z));
    const float dnorm = sqrtf(dx * dx + dy * dy + dz * dz);
    const float inv   = 1.0f / dnorm;
    const float ux = dx * inv, uy = dy * inv, uz = dz * inv;

    float sh[9];
    sh[0] = 0.28209479177387814f;
    sh[1] = -0.4886025119029199f * uy;
    sh[2] =  0.4886025119029199f * uz;
    sh[3] = -0.4886025119029199f * ux;
    sh[4] =  1.0925484305920792f * ux * uy;
    sh[5] = -1.0925484305920792f * uy * uz;
    sh[6] =  0.31539156525252005f * (2.0f * uz * uz - ux * ux - uy * uy);
    sh[7] = -1.0925484305920792f * ux * uz;
    sh[8] =  0.5462742152960396f * (ux * ux - uy * uy);

    // ---- sample geometry; ISSUE corner loads FIRST (hidden under the fold) ----
    const float tm   = tnear + ((float)s + 0.5f) * STEPF;
    const bool  mask = (s < N_INTR) && (tm < tfar) && (tfar > tnear);

    float4 gq[8][4];
    float  wcn[8];
    float  p01x = 0.f, p01y = 0.f, p01z = 0.f;

    if (mask) {
        const float px = ox + dx * tm, py = oy + dy * tm, pz = oz + dz * tm;
        p01x = fminf(fmaxf((px + RADIUS) / (2.0f * RADIUS), 0.0f), 0.999999f);
        p01y = fminf(fmaxf((py + RADIUS) / (2.0f * RADIUS), 0.0f), 0.999999f);
        p01z = fminf(fmaxf((pz + RADIUS) / (2.0f * RADIUS), 0.0f), 0.999999f);

        const float ccx = p01x * (COARSE - 1), ccy = p01y * (COARSE - 1), ccz = p01z * (COARSE - 1);
        const float fcx = ccx - floorf(ccx), fcy = ccy - floorf(ccy), fcz = ccz - floorf(ccz);
        int i0x = min(max((int)floorf(ccx), 0), COARSE - 1), i1x = min(i0x + 1, COARSE - 1);
        int i0y = min(max((int)floorf(ccy), 0), COARSE - 1), i1y = min(i0y + 1, COARSE - 1);
        int i0z = min(max((int)floorf(ccz), 0), COARSE - 1), i1z = min(i0z + 1, COARSE - 1);

        #pragma unroll
        for (int cn = 0; cn < 8; ++cn) {
            const int   ix = (cn & 4) ? i1x : i0x;
            const int   iy = (cn & 2) ? i1y : i0y;
            const int   iz = (cn & 1) ? i1z : i0z;
            const float wx = (cn & 4) ? fcx : 1.0f - fcx;
            const float wy = (cn & 2) ? fcy : 1.0f - fcy;
            const float wz = (cn & 1) ? fcz : 1.0f - fcz;
            wcn[cn] = wx * wy * wz;
            const float4* gp = reinterpret_cast<const float4*>(cgrid)
                               + ((((ix << 4) | iy) << 4) | iz) * 4;
            gq[cn][0] = gp[0]; gq[cn][1] = gp[1];
            gq[cn][2] = gp[2]; gq[cn][3] = gp[3];
        }
    }

    // ---- fold SH into dictionary; 1024 rows, 4 per thread (2 batches of 2) ----
    #pragma unroll
    for (int kk = 0; kk < 2; ++kk) {
        float4 fs[2][7];
        #pragma unroll
        for (int k = 0; k < 2; ++k) {
            const int row = tid + (kk * 2 + k) * NTHREADS;
            const float4* arow = reinterpret_cast<const float4*>(atoms) + row * 7;
            #pragma unroll
            for (int j = 0; j < 7; ++j) fs[k][j] = arow[j];
        }
        #pragma unroll
        for (int k = 0; k < 2; ++k) {
            const int row  = tid + (kk * 2 + k) * NTHREADS;
            const int cell = row >> 4;
            const int atom = row & 15;
            const float f[28] = { fs[k][0].x, fs[k][0].y, fs[k][0].z, fs[k][0].w,
                                  fs[k][1].x, fs[k][1].y, fs[k][1].z, fs[k][1].w,
                                  fs[k][2].x, fs[k][2].y, fs[k][2].z, fs[k][2].w,
                                  fs[k][3].x, fs[k][3].y, fs[k][3].z, fs[k][3].w,
                                  fs[k][4].x, fs[k][4].y, fs[k][4].z, fs[k][4].w,
                                  fs[k][5].x, fs[k][5].y, fs[k][5].z, fs[k][5].w,
                                  fs[k][6].x, fs[k][6].y, fs[k][6].z, fs[k][6].w };
            float R = 0.0f, G = 0.0f, B = 0.0f;
            #pragma unroll
            for (int h = 0; h < 9; ++h) {
                const float s_ = sh[h];
                R += s_ * f[h];
                G += s_ * f[9 + h];
                B += s_ * f[18 + h];
            }
            ldsR[cell * LDS_STRIDE + atom] = make_float4(R, G, B, f[27]);
        }
    }
    __syncthreads();

    // ---- stage B: consume corners (already landed) + LDS dict ----
    float alpha = 0.0f;
    float pr = 0.0f, pg = 0.0f, pb = 0.0f;
    float v = 1.0f;

    if (mask) {
        const float delta = STEPF * dnorm;

        float cf[16];
        #pragma unroll
        for (int a = 0; a < 16; ++a) cf[a] = 0.0f;
        #pragma unroll
        for (int cn = 0; cn < 8; ++cn) {
            const float w = wcn[cn];
            #pragma unroll
            for (int k = 0; k < 4; ++k) {
                const float4 gv = gq[cn][k];
                cf[k * 4 + 0] += w * gv.x;
                cf[k * 4 + 1] += w * gv.y;
                cf[k * 4 + 2] += w * gv.z;
                cf[k * 4 + 3] += w * gv.w;
            }
        }

        // fine-local trilinear setup
        const float pfx = p01x * COARSE, pfy = p01y * COARSE, pfz = p01z * COARSE;
        const float lfx = (pfx - floorf(pfx)) * (FINE - 1);
        const float lfy = (pfy - floorf(pfy)) * (FINE - 1);
        const float lfz = (pfz - floorf(pfz)) * (FINE - 1);
        const float ffx = lfx - floorf(lfx), ffy = lfy - floorf(lfy), ffz = lfz - floorf(lfz);
        int j0x = min(max((int)floorf(lfx), 0), FINE - 1), j1x = min(j0x + 1, FINE - 1);
        int j0y = min(max((int)floorf(lfy), 0), FINE - 1), j1y = min(j0y + 1, FINE - 1);
        int j0z = min(max((int)floorf(lfz), 0), FINE - 1), j1z = min(j0z + 1, FINE - 1);

        int   cb[8];
        float wf[8];
        #pragma unroll
        for (int c = 0; c < 8; ++c) {
            const int   jx = (c & 4) ? j1x : j0x;
            const int   jy = (c & 2) ? j1y : j0y;
            const int   jz = (c & 1) ? j1z : j0z;
            const float wx = (c & 4) ? ffx : 1.0f - ffx;
            const float wy = (c & 2) ? ffy : 1.0f - ffy;
            const float wz = (c & 1) ? ffz : 1.0f - ffz;
            wf[c] = wx * wy * wz;
            cb[c] = (((jx << 2) | jy) << 2 | jz) * LDS_STRIDE;
        }

        float o4x = 0.0f, o4y = 0.0f, o4z = 0.0f, o4w = 0.0f;
        #pragma unroll
        for (int a = 0; a < 16; ++a) {
            float tx = 0.0f, ty = 0.0f, tz = 0.0f, tw = 0.0f;
            #pragma unroll
            for (int c = 0; c < 8; ++c) {
                const float4 vv = ldsR[cb[c] + a];
                tx += wf[c] * vv.x; ty += wf[c] * vv.y;
                tz += wf[c] * vv.z; tw += wf[c] * vv.w;
            }
            o4x += cf[a] * tx; o4y += cf[a] * ty;
            o4z += cf[a] * tz; o4w += cf[a] * tw;
        }

        const float sigma = fmaxf(o4w, 0.0f);
        alpha = 1.0f - expf(-sigma * delta);
        pr = o4x; pg = o4y; pb = o4z;
    }

    if (s < N_INTR) {
        out[4 * n_rays + ray * N_INTR + s] = alpha;
        v = 1.0f - alpha + 1e-10f;
    }

    // ---- cumprod scan: wave shuffles + one barrier (4 waves) ----
    const int lane = tid & 63;
    float incl = v;
    #pragma unroll
    for (int off = 1; off < 64; off <<= 1) {
        const float t = __shfl_up(incl, off);
        if (lane >= off) incl *= t;
    }
    const int wid = tid >> 6;          // 0..3
    if (lane == 63) wtot[wid] = incl;
    __syncthreads();
    float prefix = 1.0f;
    #pragma unroll
    for (int q = 0; q < 3; ++q)
        if (q < wid) prefix *= wtot[q];
    float excl = __shfl_up(incl, 1);
    if (lane == 0) excl = 1.0f;
    const float trans = prefix * excl;
    const float w = alpha * trans;     // alpha==0 for invalid/masked -> w==0

    // ---- reductions ----
    float v0 = w * sigmoidf_(pr);
    float v1 = w * sigmoidf_(pg);
    float v2 = w * sigmoidf_(pb);
    float v3 = w * tm;
    float v4 = w;
    #pragma unroll
    for (int off = 32; off >= 1; off >>= 1) {
        v0 += __shfl_down(v0, off);
        v1 += __shfl_down(v1, off);
        v2 += __shfl_down(v2, off);
        v3 += __shfl_down(v3, off);
        v4 += __shfl_down(v4, off);
    }
    if (lane == 0) {
        partials[wid][0] = v0; partials[wid][1] = v1;
        partials[wid][2] = v2; partials[wid][3] = v3;
        partials[wid][4] = v4;
    }
    __syncthreads();
    if (tid == 0) {
        float s0 = 0.0f, s1 = 0.0f, s2 = 0.0f, s3 = 0.0f, s4 = 0.0f;
        #pragma unroll
        for (int q = 0; q < 4; ++q) {
            s0 += partials[q][0]; s1 += partials[q][1];
            s2 += partials[q][2]; s3 += partials[q][3];
            s4 += partials[q][4];
        }
        const float bg = 1.0f - s4;
        out[ray * 3 + 0] = s0 + bg;
        out[ray * 3 + 1] = s1 + bg;
        out[ray * 3 + 2] = s2 + bg;
        out[3 * n_rays + ray] = s3;                        // depth
        if (ray == 0)
            out[4 * n_rays + n_rays * N_INTR] = 0.0f;      // trailing scalar
    }
}

extern "C" void kernel_launch(void* const* d_in, const int* in_sizes, int n_in,
                              void* d_out, int out_size, void* d_ws, size_t ws_size,
                              hipStream_t stream)
{
    const float* rays_o = (const float*)d_in[0];
    const float* rays_d = (const float*)d_in[1];
    const float* cgrid  = (const float*)d_in[2];
    const float* atoms  = (const float*)d_in[3];
    float* out = (float*)d_out;

    const int n_rays = in_sizes[0] / 3;                   // 1024
    plenoxel_fwd<<<n_rays, NTHREADS, 0, stream>>>(rays_o, rays_d, cgrid, atoms, out, n_rays);
}